// Round 10
// baseline (6058.646 us; speedup 1.0000x reference)
//
#include <hip/hip_runtime.h>

typedef unsigned short u16;
typedef unsigned int u32;
typedef _Float16 f16;
typedef f16 h2 __attribute__((ext_vector_type(2)));
typedef f16 h4 __attribute__((ext_vector_type(4)));
typedef f16 h8 __attribute__((ext_vector_type(8)));
typedef u16 u16x8 __attribute__((ext_vector_type(8)));
typedef float f32x4 __attribute__((ext_vector_type(4)));

#define B_ 64
#define F_ 128
#define H_ 512
#define S_ 512
#define T_ 96
#define NB 256
#define NT 1024

// ---- workspace byte offsets (audited: each end == next start or less) ----
#define FLAG_OFF  0ul          // u32[256] @64B stride           -> 16384
#define GEN_OFF   16384ul      // u32[8] @64B stride             -> 16896
#define DEN_OFF   20480ul      // f32 [64][4]                    -> 21504
#define CQ_OFF    24576ul      // u32 [64][4][256] f16x2 c parts -> 286720
#define HPP_OFF   294912ul     // u32 [16][64][256] f16x2 hp     -> 1343488
#define OPP_OFF   1343488ul    // u32 [2][16][64][64] f16x2 out  -> 1867776
#define HNEW_OFF  1867776ul    // f32 [2][64][512]               -> 2129920
#define WTS_OFF   2129920ul    // f16 [2359296]                  -> 6848512  (r9 bug: was 2125824, overlapped HNEW[1] by 4096B)
#define ENCP_OFF  8388608ul    // f16 [64][512][512] 2*(enc@Wa2^T+ba) -> 41943040
#define ENCF_OFF  41943040ul   // f16 [64][512][512] enc         -> 75497472
// end: 75497472 (~72 MiB)

#define OPP_HALF  (16 * 64 * 64)

// f16-element offsets inside WTS
#define WA1_E  0        // [512][512]
#define WA2_E  262144   // [512][512]
#define WHH_E  524288   // [1536][512]
#define WC_E   1310720  // [1536][512]
#define WX_E   2097152  // [1536][128]
#define WOUT_E 2293760  // [128][512]
#define WTS_N  2359296

__device__ __forceinline__ float fdot2(h2 a, h2 b, float c) {
#if __has_builtin(__builtin_amdgcn_fdot2)
  return __builtin_amdgcn_fdot2(a, b, c, false);
#else
  return c + (float)a[0] * (float)b[0] + (float)a[1] * (float)b[1];
#endif
}
__device__ __forceinline__ u32 packh2(float a, float b) {
  h2 p; p[0] = (f16)a; p[1] = (f16)b;
  return __builtin_bit_cast(u32, p);
}
__device__ __forceinline__ h2 unpackh2(u32 v) { return __builtin_bit_cast(h2, v); }
__device__ __forceinline__ void xstf(float* p, float v) {
  __hip_atomic_exchange(p, v, __ATOMIC_RELAXED, __HIP_MEMORY_SCOPE_AGENT);
}
__device__ __forceinline__ void xstu(u32* p, u32 v) {
  __hip_atomic_exchange(p, v, __ATOMIC_RELAXED, __HIP_MEMORY_SCOPE_AGENT);
}
__device__ __forceinline__ float aldf(const float* p) {
  return __hip_atomic_load(p, __ATOMIC_RELAXED, __HIP_MEMORY_SCOPE_AGENT);
}
__device__ __forceinline__ u32 aldu(const u32* p) {
  return __hip_atomic_load(p, __ATOMIC_RELAXED, __HIP_MEMORY_SCOPE_AGENT);
}

// fence-free flag-array barrier — r8-proven version verbatim.
__device__ __forceinline__ void gridbar(u32* flags, u32* gen, unsigned ep) {
  __builtin_amdgcn_s_waitcnt(0);
  __syncthreads();
  const int bid = blockIdx.x, tid = threadIdx.x;
  if (bid == 0) {
    if (tid >= 64 && tid < 319) {
      u32* pf = flags + (tid - 63) * 16;
      int guard = 0;
      while (__hip_atomic_load(pf, __ATOMIC_RELAXED, __HIP_MEMORY_SCOPE_AGENT) < ep) {
        __builtin_amdgcn_s_sleep(1);
        if (++guard > (1 << 16)) break;
      }
    }
    __syncthreads();
    if (tid < 8)
      __hip_atomic_exchange(gen + tid * 16, ep, __ATOMIC_RELAXED, __HIP_MEMORY_SCOPE_AGENT);
  } else {
    if (tid == 0) {
      __hip_atomic_exchange(flags + bid * 16, ep, __ATOMIC_RELAXED, __HIP_MEMORY_SCOPE_AGENT);
      u32* pg = gen + (bid & 7) * 16;
      int guard = 0;
      while (__hip_atomic_load(pg, __ATOMIC_RELAXED, __HIP_MEMORY_SCOPE_AGENT) < ep) {
        __builtin_amdgcn_s_sleep(1);
        if (++guard > (1 << 17)) break;
      }
    }
  }
  __syncthreads();
  asm volatile("" ::: "memory");
}

// ---------------- enc f32 -> f16 linear (one-time) ----------------
__global__ __launch_bounds__(256) void transcode_enc(const float* __restrict__ enc,
                                                     f16* __restrict__ out) {
  int i = blockIdx.x * 256 + threadIdx.x;
  #pragma unroll
  for (int u = 0; u < 4; ++u) {
    int idx = i + u * 1048576;
    float4 v = ((const float4*)enc)[idx];
    h4 o = {(f16)v.x, (f16)v.y, (f16)v.z, (f16)v.w};
    ((h4*)out)[idx] = o;
  }
}

// ---------------- pack all weights to f16 (one-time) ----------------
__global__ __launch_bounds__(256) void pack_weights(
    const float* __restrict__ Wa, const float* __restrict__ Whh,
    const float* __restrict__ Wih, const float* __restrict__ Wout,
    f16* __restrict__ WTS) {
  int i = blockIdx.x * 256 + threadIdx.x;
  if (i >= WTS_N) return;
  float x;
  if (i < WA2_E) {
    int n = i >> 9, k = i & 511;
    x = Wa[(size_t)n * 1024 + k];
  } else if (i < WHH_E) {
    int j = i - WA2_E; int n = j >> 9, k = j & 511;
    x = Wa[(size_t)n * 1024 + 512 + k];
  } else if (i < WC_E) {
    int j = i - WHH_E; int n = j >> 9, k = j & 511;
    x = Whh[(size_t)n * 512 + k];
  } else if (i < WX_E) {
    int j = i - WC_E; int n = j >> 9, k = j & 511;
    x = Wih[(size_t)n * 640 + 128 + k];
  } else if (i < WOUT_E) {
    int j = i - WX_E; int n = j >> 7, k = j & 127;
    x = Wih[(size_t)n * 640 + k];
  } else {
    int j = i - WOUT_E; int n = j >> 9, k = j & 511;
    x = Wout[(size_t)n * 512 + k];
  }
  WTS[i] = (f16)x;
}

// ------- MFMA: ENCP[m][n] = 2*(sum_k ENCF[m][k]*WA2[n][k] + ba[n]), f16 -------
__global__ __launch_bounds__(256) void mfma_encproj(const u16* __restrict__ Abf,
                                                    const u16* __restrict__ Bbf,
                                                    const float* __restrict__ ba,
                                                    f16* __restrict__ C) {
  __shared__ u16 As[128 * 40];
  __shared__ u16 Bs[128 * 40];
  const int tid = threadIdx.x, lane = tid & 63, w = tid >> 6;
  const int m0 = blockIdx.x << 7, n0 = blockIdx.y << 7;
  const int r0 = lane & 15, kh = lane >> 4;
  f32x4 acc[2][8] = {};
  for (int k0 = 0; k0 < 512; k0 += 32) {
    #pragma unroll
    for (int i = 0; i < 2; ++i) {
      int e = tid + (i << 8);
      int row = e >> 2, g = e & 3;
      *(u16x8*)&As[row * 40 + (g << 3)] =
          *(const u16x8*)(Abf + (size_t)(m0 + row) * 512 + k0 + (g << 3));
      *(u16x8*)&Bs[row * 40 + (g << 3)] =
          *(const u16x8*)(Bbf + (size_t)(n0 + row) * 512 + k0 + (g << 3));
    }
    __syncthreads();
    h8 a[2], bb[8];
    #pragma unroll
    for (int r = 0; r < 2; ++r)
      a[r] = *(const h8*)&As[((w << 5) + (r << 4) + r0) * 40 + (kh << 3)];
    #pragma unroll
    for (int c = 0; c < 8; ++c)
      bb[c] = *(const h8*)&Bs[((c << 4) + r0) * 40 + (kh << 3)];
    #pragma unroll
    for (int r = 0; r < 2; ++r)
      #pragma unroll
      for (int c = 0; c < 8; ++c)
        acc[r][c] = __builtin_amdgcn_mfma_f32_16x16x32_f16(a[r], bb[c], acc[r][c], 0, 0, 0);
    __syncthreads();
  }
  #pragma unroll
  for (int c = 0; c < 8; ++c) {
    int n = n0 + (c << 4) + r0;
    float bav = ba[n];
    #pragma unroll
    for (int r = 0; r < 2; ++r) {
      int mbase = m0 + (w << 5) + (r << 4) + (kh << 2);
      #pragma unroll
      for (int t = 0; t < 4; ++t)
        C[(size_t)(mbase + t) * 512 + n] = (f16)(2.f * (acc[r][c][t] + bav));
    }
  }
}

struct Params {
  const float *hidden, *dec_input, *Wv, *bih, *bhh, *bout;
  const f16 *ENCP, *ENCF, *WA1, *WHH, *WC, *WX, *WOUT;
  u32 *CQ, *HPP, *OPP, *flags, *gen;
  float *DEN, *HNEW, *out;
};

union SMem {
  struct {
    float hpL[512];
    float cpart[16][8][65];
    float dWL[16];
  } a;
  struct {
    h2 hh2[4][256] __attribute__((aligned(16)));
    h2 ch2[4][256] __attribute__((aligned(16)));
    h2 xh2[4][64] __attribute__((aligned(16)));
    h2 hn2[4][16] __attribute__((aligned(16)));
    float hfL[4][32];
    float invL[4];
    float g1[384], g2[384];
  } bc;
};

__global__ __launch_bounds__(NT, 1) void decoder2(Params p) {
  __shared__ SMem sm;
  const int bid = blockIdx.x, tid = threadIdx.x;
  const int lane = tid & 63, w = tid >> 6;
  unsigned ep = 0;

  // A role
  const int ab = bid >> 2, asq = bid & 3;
  // BC role
  const int bg = bid >> 4, rs = bid & 15;
  const int hsb = rs * 32;

  float wv2[8], wvs = 0.f;
  {
    const float* wp = p.Wv + lane * 8;
    #pragma unroll
    for (int e = 0; e < 8; ++e) { float v = wp[e]; wv2[e] = -2.f * v; wvs += v; }
  }

  // ================= init: hp-partials from hidden; HNEW[0] =================
  if (tid < 128) {
    int b4 = tid >> 5, r = tid & 31;
    float v = p.hidden[(size_t)(bg * 4 + b4) * 512 + hsb + r];
    float vp = __shfl_down(v, 1);
    if (!(r & 1)) sm.bc.hn2[b4][r >> 1] = h2{(f16)v, (f16)vp};
  }
  if (rs == 0) {
    #pragma unroll
    for (int rep = 0; rep < 2; ++rep) {
      int idx = rep * NT + tid;
      int b4 = idx >> 9, i = idx & 511;
      xstf(p.HNEW + (size_t)(bg * 4 + b4) * 512 + i,
           p.hidden[(size_t)(bg * 4 + b4) * 512 + i]);
    }
  }
  __syncthreads();
  {
    int b4 = tid >> 8, r2 = tid & 255;
    int b = bg * 4 + b4;
    const f16* w0 = p.WA1 + (size_t)(2 * r2) * 512 + hsb;
    float a0 = 0.f, a1 = 0.f;
    #pragma unroll
    for (int k4 = 0; k4 < 4; ++k4) {
      h8 hv = *(const h8*)&sm.bc.hn2[b4][k4 * 4];
      h8 wv0 = *(const h8*)(w0 + k4 * 8);
      h8 wv1 = *(const h8*)(w0 + 512 + k4 * 8);
      const h2 *hq = (const h2*)&hv, *q0 = (const h2*)&wv0, *q1 = (const h2*)&wv1;
      #pragma unroll
      for (int e = 0; e < 4; ++e) {
        a0 = fdot2(hq[e], q0[e], a0);
        a1 = fdot2(hq[e], q1[e], a1);
      }
    }
    xstu(p.HPP + ((rs * 64 + b) << 8) + r2, packh2(2.f * a0, 2.f * a1));
  }
  gridbar(p.flags, p.gen, ++ep);

  for (int t = 0; t < T_; ++t) {
    // ================= phase A: scores + exp + c-partials =================
    {
      if (tid < 256) {
        float s0 = 0.f, s1 = 0.f;
        #pragma unroll
        for (int sl = 0; sl < 16; ++sl) {
          h2 v = unpackh2(aldu(p.HPP + ((sl * 64 + ab) << 8) + tid));
          s0 += (float)v[0]; s1 += (float)v[1];
        }
        sm.a.hpL[2 * tid] = s0; sm.a.hpL[2 * tid + 1] = s1;
      }
      __syncthreads();
      float hp8[8];
      *(float4*)hp8 = *(const float4*)&sm.a.hpL[lane * 8];
      *(float4*)(hp8 + 4) = *(const float4*)&sm.a.hpL[lane * 8 + 4];
      const size_t sbase = (size_t)ab * 512 + asq * 128 + w * 8;
      const f16* pb = p.ENCP + (sbase << 9) + lane * 8;
      const f16* eb = p.ENCF + (sbase << 9) + lane * 8;
      float c8[8] = {};
      float den = 0.f;
      #pragma unroll
      for (int i = 0; i < 8; ++i) {
        h8 pv = *(const h8*)(pb + ((size_t)i << 9));
        float acc = wvs;
        #pragma unroll
        for (int e = 0; e < 8; ++e) {
          float e2 = __expf(hp8[e] + (float)pv[e]);
          acc += wv2[e] * __builtin_amdgcn_rcpf(e2 + 1.f);
        }
        #pragma unroll
        for (int off = 32; off; off >>= 1) acc += __shfl_xor(acc, off);
        float es = __expf(acc);   // |score| <= ~11: un-normalized exp safe
        den += es;
        h8 ev = *(const h8*)(eb + ((size_t)i << 9));
        #pragma unroll
        for (int e = 0; e < 8; ++e) c8[e] += es * (float)ev[e];
      }
      #pragma unroll
      for (int e = 0; e < 8; ++e) sm.a.cpart[w][e][lane] = c8[e];
      if (lane == 0) sm.a.dWL[w] = den;
      __syncthreads();
      if (tid < 256) {
        int h0 = 2 * tid, h1 = 2 * tid + 1;
        float v0 = 0.f, v1 = 0.f;
        #pragma unroll
        for (int ww = 0; ww < 16; ++ww) {
          v0 += sm.a.cpart[ww][h0 & 7][h0 >> 3];
          v1 += sm.a.cpart[ww][h1 & 7][h1 >> 3];
        }
        xstu(p.CQ + (((ab << 2) | asq) << 8) + tid,
             packh2(v0 * 1.220703125e-4f, v1 * 1.220703125e-4f));
      } else if (tid == 256) {
        float d = 0.f;
        #pragma unroll
        for (int i = 0; i < 16; ++i) d += sm.a.dWL[i];
        xstf(p.DEN + (ab << 2) + asq, d);
      }
    }
    gridbar(p.flags, p.gen, ++ep);

    // ================= phase BC =================
    {
      float* HNc = p.HNEW + (t & 1) * 32768;
      float* HNn = p.HNEW + ((t + 1) & 1) * 32768;
      const u32* OPPc = p.OPP + (t & 1) * OPP_HALF;
      u32* OPPn = p.OPP + ((t + 1) & 1) * OPP_HALF;

      // S1: invL, h(t) load, x assembly (+out write)
      if (tid < 4) {
        float s = 0.f;
        #pragma unroll
        for (int sq = 0; sq < 4; ++sq) s += aldf(p.DEN + ((bg * 4 + tid) << 2) + sq);
        sm.bc.invL[tid] = 8192.f * __builtin_amdgcn_rcpf(s);
      }
      #pragma unroll
      for (int rep = 0; rep < 2; ++rep) {
        int idx = rep * NT + tid;
        int b4 = idx >> 9, i = idx & 511;
        float v = aldf(HNc + (size_t)(bg * 4 + b4) * 512 + i);
        float vp = __shfl_xor(v, 1);
        if (!(i & 1)) sm.bc.hh2[b4][i >> 1] = h2{(f16)v, (f16)vp};
        unsigned d = (unsigned)(i - hsb);
        if (d < 32u) sm.bc.hfL[b4][d] = v;
      }
      if (tid < 256) {
        int b4 = tid >> 6, nn = tid & 63;
        int b = bg * 4 + b4;
        float x0, x1;
        if (t == 0) {
          x0 = p.dec_input[b * 128 + 2 * nn];
          x1 = p.dec_input[b * 128 + 2 * nn + 1];
        } else {
          x0 = p.bout[2 * nn]; x1 = p.bout[2 * nn + 1];
          #pragma unroll
          for (int sl = 0; sl < 16; ++sl) {
            h2 v = unpackh2(aldu(OPPc + ((sl * 64 + b) << 6) + nn));
            x0 += (float)v[0]; x1 += (float)v[1];
          }
          if (rs == b4)
            *(float2*)&p.out[((size_t)b * T_ + (t - 1)) * F_ + 2 * nn] = float2{x0, x1};
        }
        sm.bc.xh2[b4][nn] = h2{(f16)x0, (f16)x1};
      }
      __syncthreads();
      // S2: c assembly
      {
        int b4 = tid >> 8, pp = tid & 255;
        int b = bg * 4 + b4;
        float lo = 0.f, hi = 0.f;
        #pragma unroll
        for (int sq = 0; sq < 4; ++sq) {
          h2 v = unpackh2(aldu(p.CQ + (((b << 2) | sq) << 8) + pp));
          lo += (float)v[0]; hi += (float)v[1];
        }
        float inv = sm.bc.invL[b4];
        sm.bc.ch2[b4][pp] = h2{(f16)(lo * inv), (f16)(hi * inv)};
      }
      __syncthreads();
      // S3: gates
      if (tid < 384) {
        int b4 = tid / 96, rem = tid % 96, g = rem >> 5, r = rem & 31;
        int j = g * 512 + hsb + r;
        const f16* wc = p.WC + (size_t)j * 512;
        const f16* wh = p.WHH + (size_t)j * 512;
        const f16* wx = p.WX + (size_t)j * 128;
        float gc = 0.f, gh = 0.f, gx = 0.f;
        #pragma unroll 4
        for (int k4 = 0; k4 < 64; ++k4) {
          h8 cv = *(const h8*)&sm.bc.ch2[b4][k4 * 4];
          h8 hv = *(const h8*)&sm.bc.hh2[b4][k4 * 4];
          h8 wcv = *(const h8*)(wc + k4 * 8);
          h8 whv = *(const h8*)(wh + k4 * 8);
          const h2 *cq = (const h2*)&cv, *hq = (const h2*)&hv;
          const h2 *wcq = (const h2*)&wcv, *whq = (const h2*)&whv;
          #pragma unroll
          for (int e = 0; e < 4; ++e) {
            gc = fdot2(cq[e], wcq[e], gc);
            gh = fdot2(hq[e], whq[e], gh);
          }
        }
        #pragma unroll
        for (int k4 = 0; k4 < 16; ++k4) {
          h8 xv = *(const h8*)&sm.bc.xh2[b4][k4 * 4];
          h8 wxv = *(const h8*)(wx + k4 * 8);
          const h2 *xq = (const h2*)&xv, *wxq = (const h2*)&wxv;
          #pragma unroll
          for (int e = 0; e < 4; ++e) gx = fdot2(xq[e], wxq[e], gx);
        }
        sm.bc.g1[tid] = gc + gx + p.bih[j];
        sm.bc.g2[tid] = gh + p.bhh[j];
      }
      __syncthreads();
      // S4: gate nonlinearity + h update
      if (tid < 128) {
        int b4 = tid >> 5, r = tid & 31;
        int b = bg * 4 + b4;
        int i0 = b4 * 96 + r;
        float rr = __builtin_amdgcn_rcpf(1.f + __expf(-(sm.bc.g1[i0] + sm.bc.g2[i0])));
        float zz = __builtin_amdgcn_rcpf(1.f + __expf(-(sm.bc.g1[i0 + 32] + sm.bc.g2[i0 + 32])));
        float narg = sm.bc.g1[i0 + 64] + rr * sm.bc.g2[i0 + 64];
        float nn = 1.f - 2.f * __builtin_amdgcn_rcpf(1.f + __expf(2.f * narg));
        float hn = (1.f - zz) * nn + zz * sm.bc.hfL[b4][r];
        xstf(HNn + (size_t)b * 512 + hsb + r, hn);
        float vp = __shfl_down(hn, 1);
        if (!(r & 1)) sm.bc.hn2[b4][r >> 1] = h2{(f16)hn, (f16)vp};
      }
      __syncthreads();
      // S5: hp-partials (all threads) + out-partials (tid<256)
      {
        int b4 = tid >> 8, r2 = tid & 255;
        int b = bg * 4 + b4;
        const f16* w0 = p.WA1 + (size_t)(2 * r2) * 512 + hsb;
        float a0 = 0.f, a1 = 0.f;
        #pragma unroll
        for (int k4 = 0; k4 < 4; ++k4) {
          h8 hv = *(const h8*)&sm.bc.hn2[b4][k4 * 4];
          h8 wv0 = *(const h8*)(w0 + k4 * 8);
          h8 wv1 = *(const h8*)(w0 + 512 + k4 * 8);
          const h2 *hq = (const h2*)&hv, *q0 = (const h2*)&wv0, *q1 = (const h2*)&wv1;
          #pragma unroll
          for (int e = 0; e < 4; ++e) {
            a0 = fdot2(hq[e], q0[e], a0);
            a1 = fdot2(hq[e], q1[e], a1);
          }
        }
        xstu(p.HPP + ((rs * 64 + b) << 8) + r2, packh2(2.f * a0, 2.f * a1));
      }
      if (tid < 256) {
        int b4 = tid >> 6, n2 = tid & 63;
        int b = bg * 4 + b4;
        const f16* w0 = p.WOUT + (size_t)(2 * n2) * 512 + hsb;
        float a0 = 0.f, a1 = 0.f;
        #pragma unroll
        for (int k4 = 0; k4 < 4; ++k4) {
          h8 hv = *(const h8*)&sm.bc.hn2[b4][k4 * 4];
          h8 wv0 = *(const h8*)(w0 + k4 * 8);
          h8 wv1 = *(const h8*)(w0 + 512 + k4 * 8);
          const h2 *hq = (const h2*)&hv, *q0 = (const h2*)&wv0, *q1 = (const h2*)&wv1;
          #pragma unroll
          for (int e = 0; e < 4; ++e) {
            a0 = fdot2(hq[e], q0[e], a0);
            a1 = fdot2(hq[e], q1[e], a1);
          }
        }
        xstu(OPPn + ((rs * 64 + b) << 6) + n2, packh2(a0, a1));
      }
    }
    gridbar(p.flags, p.gen, ++ep);
  }

  // ================= epilogue: write out[:, T-1, :] =================
  if (tid < 256) {
    int b4 = tid >> 6, nn = tid & 63;
    int b = bg * 4 + b4;
    if (rs == b4) {
      const u32* OPPl = p.OPP + (T_ & 1) * OPP_HALF;
      float x0 = p.bout[2 * nn], x1 = p.bout[2 * nn + 1];
      #pragma unroll
      for (int sl = 0; sl < 16; ++sl) {
        h2 v = unpackh2(aldu(OPPl + ((sl * 64 + b) << 6) + nn));
        x0 += (float)v[0]; x1 += (float)v[1];
      }
      *(float2*)&p.out[((size_t)b * T_ + (T_ - 1)) * F_ + 2 * nn] = float2{x0, x1};
    }
  }
}

extern "C" void kernel_launch(void* const* d_in, const int* in_sizes, int n_in,
                              void* d_out, int out_size, void* d_ws, size_t ws_size,
                              hipStream_t stream) {
  const float* dec_input = (const float*)d_in[0];
  const float* hidden    = (const float*)d_in[1];
  const float* enc       = (const float*)d_in[2];
  // d_in[3] expected_outputs, d_in[4] dec_output_len (fixed 96) unused
  const float* Wa   = (const float*)d_in[5];
  const float* ba   = (const float*)d_in[6];
  const float* Wv   = (const float*)d_in[7];
  // d_in[8] bv cancels in softmax
  const float* Wih  = (const float*)d_in[9];
  const float* bih  = (const float*)d_in[10];
  const float* Whh  = (const float*)d_in[11];
  const float* bhh  = (const float*)d_in[12];
  const float* Wout = (const float*)d_in[13];
  const float* bout = (const float*)d_in[14];

  char* ws = (char*)d_ws;
  f16* WTS  = (f16*)(ws + WTS_OFF);
  f16* ENCP = (f16*)(ws + ENCP_OFF);
  f16* ENCF = (f16*)(ws + ENCF_OFF);

  Params p;
  p.hidden = hidden; p.dec_input = dec_input; p.Wv = Wv;
  p.bih = bih; p.bhh = bhh; p.bout = bout;
  p.ENCP = ENCP; p.ENCF = ENCF;
  p.WA1 = WTS + WA1_E; p.WHH = WTS + WHH_E; p.WC = WTS + WC_E;
  p.WX = WTS + WX_E; p.WOUT = WTS + WOUT_E;
  p.CQ = (u32*)(ws + CQ_OFF); p.HPP = (u32*)(ws + HPP_OFF);
  p.OPP = (u32*)(ws + OPP_OFF);
  p.flags = (u32*)(ws + FLAG_OFF); p.gen = (u32*)(ws + GEN_OFF);
  p.DEN = (float*)(ws + DEN_OFF); p.HNEW = (float*)(ws + HNEW_OFF);
  p.out = (float*)d_out;

  hipMemsetAsync(ws, 0, 20480, stream);   // flags + gen
  hipLaunchKernelGGL(transcode_enc, dim3(4096), dim3(256), 0, stream, enc, ENCF);
  hipLaunchKernelGGL(pack_weights, dim3(9216), dim3(256), 0, stream,
                     Wa, Whh, Wih, Wout, WTS);
  hipLaunchKernelGGL(mfma_encproj, dim3(256, 4), dim3(256), 0, stream,
                     (const u16*)ENCF, (const u16*)(WTS + WA2_E), ba, ENCP);

  void* args[] = {&p};
  hipLaunchCooperativeKernel((void*)decoder2, dim3(NB), dim3(NT), args, 0,
                             stream);
}